// Round 1
// baseline (589.992 us; speedup 1.0000x reference)
//
#include <hip/hip_runtime.h>
#include <stdint.h>

#define DIM   1024
#define INTER 2048
#define NEXP  8

typedef _Float16 f16;
typedef __attribute__((ext_vector_type(8))) _Float16 f16x8;
typedef __attribute__((ext_vector_type(4))) float    f32x4;

// ---------------- async global->LDS (16B per lane) ----------------
static __device__ __forceinline__ void gload16(const void* gsrc, void* lds) {
    __builtin_amdgcn_global_load_lds(
        (const __attribute__((address_space(1))) uint32_t*)gsrc,
        (__attribute__((address_space(3))) uint32_t*)lds,
        16, 0, 0);
}

// ---------------- x: fp32 -> fp16 ----------------
__global__ void convert_x_kernel(const float* __restrict__ x, f16* __restrict__ xh, int nTotal) {
    int i = (blockIdx.x * 256 + threadIdx.x) * 8;
    if (i >= nTotal) return;
    f16x8 o;
    #pragma unroll
    for (int j = 0; j < 8; ++j) o[j] = (f16)x[i + j];
    *(f16x8*)(xh + i) = o;
}

// ---------------- W[e][K][N] fp32 -> Wt[e][N][K] fp16 (LDS-tiled transpose) ----------------
__global__ void transpose_conv_kernel(const float* __restrict__ W, f16* __restrict__ Wt, int K, int N) {
    __shared__ f16 tile[64][65];
    const int e  = blockIdx.z;
    const int kb = blockIdx.y * 64;
    const int nb = blockIdx.x * 64;
    const int tx = threadIdx.x & 63;
    const int ty = threadIdx.x >> 6;
    const float* We  = W  + (size_t)e * K * N;
    f16*         Wte = Wt + (size_t)e * K * N;
    #pragma unroll
    for (int i = 0; i < 16; ++i) {
        int k = ty + i * 4;
        tile[k][tx] = (f16)We[(size_t)(kb + k) * N + nb + tx];
    }
    __syncthreads();
    #pragma unroll
    for (int i = 0; i < 16; ++i) {
        int n = ty + i * 4;
        Wte[(size_t)(nb + n) * K + kb + tx] = tile[tx][n];
    }
}

// ---------------- gate: sigmoid scores, top-2, normalized weights ----------------
__global__ void gate_kernel(const float* __restrict__ x, const float* __restrict__ Wg,
                            float* __restrict__ gw, int* __restrict__ gidx,
                            int* __restrict__ counts, int T) {
    const int tok  = (int)((blockIdx.x * (size_t)blockDim.x + threadIdx.x) >> 6);
    const int lane = threadIdx.x & 63;
    if (tok >= T) return;
    const float* xr = x + (size_t)tok * DIM;
    float s[NEXP];
    #pragma unroll
    for (int e = 0; e < NEXP; ++e) s[e] = 0.f;
    for (int i = lane; i < DIM; i += 64) {
        float xv = xr[i];
        #pragma unroll
        for (int e = 0; e < NEXP; ++e) s[e] += xv * Wg[e * DIM + i];
    }
    #pragma unroll
    for (int e = 0; e < NEXP; ++e) {
        #pragma unroll
        for (int off = 32; off > 0; off >>= 1) s[e] += __shfl_xor(s[e], off);
    }
    if (lane == 0) {
        float sc[NEXP];
        #pragma unroll
        for (int e = 0; e < NEXP; ++e) sc[e] = 1.f / (1.f + expf(-s[e]));
        int i0 = 0;
        #pragma unroll
        for (int e = 1; e < NEXP; ++e) if (sc[e] > sc[i0]) i0 = e;
        int i1 = -1;
        #pragma unroll
        for (int e = 0; e < NEXP; ++e) if (e != i0 && (i1 < 0 || sc[e] > sc[i1])) i1 = e;
        float w0 = sc[i0], w1 = sc[i1];
        float inv = 1.f / (w0 + w1);
        gw[2 * tok + 0] = w0 * inv;
        gw[2 * tok + 1] = w1 * inv;
        gidx[2 * tok + 0] = i0;
        gidx[2 * tok + 1] = i1;
        atomicAdd(&counts[i0], 1);
        atomicAdd(&counts[i1], 1);
    }
}

// ---------------- exclusive scan over 8 experts ----------------
__global__ void scan_kernel(const int* __restrict__ counts, int* __restrict__ offsets,
                            int* __restrict__ cursor) {
    if (threadIdx.x == 0 && blockIdx.x == 0) {
        int acc = 0;
        for (int e = 0; e < NEXP; ++e) {
            offsets[e] = acc;
            cursor[e]  = acc;
            acc += counts[e];
        }
        offsets[NEXP] = acc;
    }
}

// ---------------- scatter tokens into per-expert row lists ----------------
__global__ void scatter_kernel(const int* __restrict__ gidx, int* __restrict__ cursor,
                               int* __restrict__ tor, int* __restrict__ ros, int T) {
    int t = blockIdx.x * 256 + threadIdx.x;
    if (t >= T) return;
    #pragma unroll
    for (int k = 0; k < 2; ++k) {
        int e   = gidx[2 * t + k];
        int pos = atomicAdd(&cursor[e], 1);
        tor[pos]        = t;
        ros[2 * t + k]  = pos;
    }
}

// ---------------- grouped GEMM: C[rows, ND] = A(gathered)[rows, KD] x Bt[e][ND,KD]^T + bias ----------------
template<int KD, int ND, bool RELU, bool GATHER>
__global__ __launch_bounds__(256)
void moe_gemm_kernel(const f16* __restrict__ Abase, const f16* __restrict__ Bt,
                     const float* __restrict__ bias, const int* __restrict__ offsets,
                     const int* __restrict__ tok, f16* __restrict__ Cout) {
    const int e      = blockIdx.z;
    const int rowBeg = offsets[e];
    const int rowEnd = offsets[e + 1];
    const int row0   = rowBeg + blockIdx.y * 128;
    if (row0 >= rowEnd) return;
    const int n0   = blockIdx.x * 128;
    const int tid  = threadIdx.x;
    const int lane = tid & 63;
    const int wid  = tid >> 6;
    const int wr   = (wid >> 1) * 64;
    const int wc   = (wid & 1) * 64;

    __shared__ __align__(16) f16 As[128 * 32];
    __shared__ __align__(16) f16 Bs[128 * 32];

    const f16* Bte = Bt + (size_t)e * ND * KD;

    // per-thread A-row indices for the two staging chunks (clamped, gathered)
    int arow[2];
    #pragma unroll
    for (int i = 0; i < 2; ++i) {
        int c  = i * 256 + tid;
        int r  = c >> 2;
        int gr = row0 + r;
        if (gr >= rowEnd) gr = rowEnd - 1;
        arow[i] = GATHER ? tok[gr] : gr;
    }

    f32x4 acc[4][4] = {};

    const int nK = KD / 32;
    for (int kt = 0; kt < nK; ++kt) {
        const int k0 = kt * 32;
        #pragma unroll
        for (int i = 0; i < 2; ++i) {   // stage A tile [128 rows][32 k]
            int c  = i * 256 + tid;
            int kc = c & 3;
            gload16(Abase + (size_t)arow[i] * KD + k0 + kc * 8, &As[c * 8]);
        }
        #pragma unroll
        for (int i = 0; i < 2; ++i) {   // stage B tile [128 n][32 k]
            int c = i * 256 + tid;
            int r = c >> 2, kc = c & 3;
            gload16(Bte + (size_t)(n0 + r) * KD + k0 + kc * 8, &Bs[c * 8]);
        }
        __syncthreads();

        const int koff = (lane >> 4) * 8;
        f16x8 af[4], bfr[4];
        #pragma unroll
        for (int m = 0; m < 4; ++m)
            af[m] = *(const f16x8*)&As[(wr + m * 16 + (lane & 15)) * 32 + koff];
        #pragma unroll
        for (int n = 0; n < 4; ++n)
            bfr[n] = *(const f16x8*)&Bs[(wc + n * 16 + (lane & 15)) * 32 + koff];
        #pragma unroll
        for (int m = 0; m < 4; ++m)
            #pragma unroll
            for (int n = 0; n < 4; ++n)
                acc[m][n] = __builtin_amdgcn_mfma_f32_16x16x32_f16(af[m], bfr[n], acc[m][n], 0, 0, 0);
        __syncthreads();
    }

    const int rowsValid = rowEnd - row0;
    #pragma unroll
    for (int m = 0; m < 4; ++m) {
        #pragma unroll
        for (int n = 0; n < 4; ++n) {
            #pragma unroll
            for (int j = 0; j < 4; ++j) {
                int rl  = wr + m * 16 + ((lane >> 4) << 2) + j;
                int col = n0 + wc + n * 16 + (lane & 15);
                if (rl < rowsValid) {
                    float v = acc[m][n][j] + bias[e * ND + col];
                    if (RELU) v = fmaxf(v, 0.f);
                    Cout[(size_t)(row0 + rl) * ND + col] = (f16)v;
                }
            }
        }
    }
}

// ---------------- combine: y[t] = w0*eo[r0] + w1*eo[r1] ----------------
__global__ void combine_kernel(const f16* __restrict__ eo, const int* __restrict__ ros,
                               const float* __restrict__ gw, float* __restrict__ y, int T) {
    int gid = blockIdx.x * 256 + threadIdx.x;
    int t   = gid >> 7;
    if (t >= T) return;
    int c0 = (gid & 127) * 8;
    int r0 = ros[2 * t], r1 = ros[2 * t + 1];
    float w0 = gw[2 * t], w1 = gw[2 * t + 1];
    f16x8 v0 = *(const f16x8*)(eo + (size_t)r0 * DIM + c0);
    f16x8 v1 = *(const f16x8*)(eo + (size_t)r1 * DIM + c0);
    f32x4 o0, o1;
    #pragma unroll
    for (int j = 0; j < 4; ++j) o0[j] = w0 * (float)v0[j] + w1 * (float)v1[j];
    #pragma unroll
    for (int j = 0; j < 4; ++j) o1[j] = w0 * (float)v0[4 + j] + w1 * (float)v1[4 + j];
    *(f32x4*)(y + (size_t)t * DIM + c0)     = o0;
    *(f32x4*)(y + (size_t)t * DIM + c0 + 4) = o1;
}

extern "C" void kernel_launch(void* const* d_in, const int* in_sizes, int n_in,
                              void* d_out, int out_size, void* d_ws, size_t ws_size,
                              hipStream_t stream) {
    const float* x  = (const float*)d_in[0];
    const float* Wg = (const float*)d_in[1];
    const float* W1 = (const float*)d_in[2];
    const float* b1 = (const float*)d_in[3];
    const float* W2 = (const float*)d_in[4];
    const float* b2 = (const float*)d_in[5];
    float* y = (float*)d_out;
    const int T = in_sizes[0] / DIM;   // 8192

    char* ws = (char*)d_ws;
    size_t off = 0;
    auto alloc = [&](size_t bytes) -> char* {
        char* p = ws + off;
        off += (bytes + 255) & ~(size_t)255;
        return p;
    };
    f16* xh   = (f16*)alloc((size_t)T * DIM * 2);
    f16* w1t  = (f16*)alloc((size_t)NEXP * DIM * INTER * 2);
    f16* w2t  = (f16*)alloc((size_t)NEXP * DIM * INTER * 2);
    f16* h    = (f16*)alloc((size_t)2 * T * INTER * 2);
    f16* eo   = (f16*)alloc((size_t)2 * T * DIM * 2);
    float* gw = (float*)alloc((size_t)T * 2 * 4);
    int* gidx = (int*)alloc((size_t)T * 2 * 4);
    int* ros  = (int*)alloc((size_t)T * 2 * 4);
    int* tor  = (int*)alloc((size_t)2 * T * 4);
    int* ctrl = (int*)alloc(64 * 4);
    int* counts  = ctrl;
    int* offsets = ctrl + 8;
    int* cursor  = ctrl + 17;

    hipMemsetAsync(counts, 0, 8 * sizeof(int), stream);

    convert_x_kernel<<<(T * DIM / 8 + 255) / 256, 256, 0, stream>>>(x, xh, T * DIM);
    transpose_conv_kernel<<<dim3(INTER / 64, DIM / 64, NEXP), 256, 0, stream>>>(W1, w1t, DIM, INTER);
    transpose_conv_kernel<<<dim3(DIM / 64, INTER / 64, NEXP), 256, 0, stream>>>(W2, w2t, INTER, DIM);
    gate_kernel<<<T / 4, 256, 0, stream>>>(x, Wg, gw, gidx, counts, T);
    scan_kernel<<<1, 64, 0, stream>>>(counts, offsets, cursor);
    scatter_kernel<<<(T + 255) / 256, 256, 0, stream>>>(gidx, cursor, tor, ros, T);
    moe_gemm_kernel<DIM, INTER, true, true>
        <<<dim3(INTER / 128, 64, NEXP), 256, 0, stream>>>(xh, w1t, b1, offsets, tor, h);
    moe_gemm_kernel<INTER, DIM, false, false>
        <<<dim3(DIM / 128, 64, NEXP), 256, 0, stream>>>(h, w2t, b2, offsets, tor, eo);
    combine_kernel<<<(T * DIM / 8 + 255) / 256, 256, 0, stream>>>(eo, ros, gw, y, T);
}

// Round 2
// 355.439 us; speedup vs baseline: 1.6599x; 1.6599x over previous
//
#include <hip/hip_runtime.h>
#include <stdint.h>

#define DIM   1024
#define INTER 2048
#define NEXP  8

typedef _Float16 f16;
typedef __attribute__((ext_vector_type(4))) _Float16 f16x4;
typedef __attribute__((ext_vector_type(8))) _Float16 f16x8;
typedef __attribute__((ext_vector_type(4))) float    f32x4;

// ---------------- async global->LDS (16B per lane) ----------------
static __device__ __forceinline__ void gload16(const void* gsrc, void* lds) {
    __builtin_amdgcn_global_load_lds(
        (const __attribute__((address_space(1))) uint32_t*)gsrc,
        (__attribute__((address_space(3))) uint32_t*)lds,
        16, 0, 0);
}

// ---------------- fused gate (sigmoid top-2) + x fp32->fp16 conversion ----------------
// one wave per token; float4-vectorized; NO atomics.
__global__ void gate_convert_kernel(const float* __restrict__ x, const float* __restrict__ Wg,
                                    f16* __restrict__ xh, float* __restrict__ gw,
                                    int* __restrict__ gidx, int T) {
    const int tok  = (int)((blockIdx.x * (size_t)blockDim.x + threadIdx.x) >> 6);
    const int lane = threadIdx.x & 63;
    if (tok >= T) return;
    const float4* xr  = (const float4*)(x + (size_t)tok * DIM);
    f16*          xhr = xh + (size_t)tok * DIM;
    float s[NEXP];
    #pragma unroll
    for (int e = 0; e < NEXP; ++e) s[e] = 0.f;
    #pragma unroll
    for (int it = 0; it < 4; ++it) {
        int i = it * 64 + lane;               // float4 index within row (256 total)
        float4 xv = xr[i];
        f16x4 hv = { (f16)xv.x, (f16)xv.y, (f16)xv.z, (f16)xv.w };
        *(f16x4*)(xhr + i * 4) = hv;
        #pragma unroll
        for (int e = 0; e < NEXP; ++e) {
            float4 wv = ((const float4*)(Wg + e * DIM))[i];
            s[e] += xv.x * wv.x + xv.y * wv.y + xv.z * wv.z + xv.w * wv.w;
        }
    }
    #pragma unroll
    for (int e = 0; e < NEXP; ++e) {
        #pragma unroll
        for (int off = 32; off > 0; off >>= 1) s[e] += __shfl_xor(s[e], off);
    }
    if (lane == 0) {
        float sc[NEXP];
        #pragma unroll
        for (int e = 0; e < NEXP; ++e) sc[e] = 1.f / (1.f + expf(-s[e]));
        int i0 = 0;
        #pragma unroll
        for (int e = 1; e < NEXP; ++e) if (sc[e] > sc[i0]) i0 = e;
        int i1 = -1;
        #pragma unroll
        for (int e = 0; e < NEXP; ++e) if (e != i0 && (i1 < 0 || sc[e] > sc[i1])) i1 = e;
        float w0 = sc[i0], w1 = sc[i1];
        float inv = 1.f / (w0 + w1);
        gw[2 * tok + 0] = w0 * inv;
        gw[2 * tok + 1] = w1 * inv;
        gidx[2 * tok + 0] = i0;
        gidx[2 * tok + 1] = i1;
    }
}

// ---------------- W[e][K][N] fp32 -> Wt[e][N][K] fp16 (LDS-tiled transpose) ----------------
__global__ void transpose_conv_kernel(const float* __restrict__ W, f16* __restrict__ Wt, int K, int N) {
    __shared__ f16 tile[64][65];
    const int e  = blockIdx.z;
    const int kb = blockIdx.y * 64;
    const int nb = blockIdx.x * 64;
    const int tx = threadIdx.x & 63;
    const int ty = threadIdx.x >> 6;
    const float* We  = W  + (size_t)e * K * N;
    f16*         Wte = Wt + (size_t)e * K * N;
    #pragma unroll
    for (int i = 0; i < 16; ++i) {
        int k = ty + i * 4;
        tile[k][tx] = (f16)We[(size_t)(kb + k) * N + nb + tx];
    }
    __syncthreads();
    #pragma unroll
    for (int i = 0; i < 16; ++i) {
        int n = ty + i * 4;
        Wte[(size_t)(nb + n) * K + kb + tx] = tile[tx][n];
    }
}

// ---------------- routing: histogram + scan + deterministic rank scatter, ONE block, no atomics ----------------
__global__ __launch_bounds__(1024)
void route_kernel(const int* __restrict__ gidx, int* __restrict__ offsets,
                  int* __restrict__ tor, int* __restrict__ ros, int T) {
    const int tid  = threadIdx.x;
    const int lane = tid & 63;
    const int wv   = tid >> 6;         // 16 waves
    const int NE   = 2 * T;            // 16384 entries, divisible by 1024
    __shared__ int wc[16][NEXP];
    __shared__ int rb[NEXP];

    // ---- pass 1: per-thread counts (static-indexed), wave reduce, block reduce ----
    int c[NEXP];
    #pragma unroll
    for (int e = 0; e < NEXP; ++e) c[e] = 0;
    for (int i = tid; i < NE; i += 1024) {
        int g = gidx[i];
        #pragma unroll
        for (int e = 0; e < NEXP; ++e) c[e] += (g == e) ? 1 : 0;
    }
    #pragma unroll
    for (int e = 0; e < NEXP; ++e) {
        #pragma unroll
        for (int off = 32; off > 0; off >>= 1) c[e] += __shfl_xor(c[e], off);
    }
    if (lane == 0) {
        #pragma unroll
        for (int e = 0; e < NEXP; ++e) wc[wv][e] = c[e];
    }
    __syncthreads();
    if (tid == 0) {
        int acc = 0;
        for (int e = 0; e < NEXP; ++e) {
            int t = 0;
            for (int w2 = 0; w2 < 16; ++w2) t += wc[w2][e];
            offsets[e] = acc;
            rb[e] = acc;
            acc += t;
        }
        offsets[NEXP] = acc;
    }
    __syncthreads();

    // ---- pass 2: in-order scatter via ballot ranks ----
    for (int base = 0; base < NE; base += 1024) {
        int i = base + tid;
        int g = gidx[i];
        int myrank = 0;
        #pragma unroll
        for (int e = 0; e < NEXP; ++e) {
            unsigned long long m = __ballot(g == e);
            if (g == e) myrank = __popcll(m & ((1ull << lane) - 1ull));
            if (lane == 0) wc[wv][e] = __popcll(m);
        }
        __syncthreads();
        int pre = 0;
        for (int w2 = 0; w2 < wv; ++w2) pre += wc[w2][g];
        int pos = rb[g] + pre + myrank;
        tor[pos] = i >> 1;
        ros[i]   = pos;
        __syncthreads();
        if (tid < NEXP) {
            int t = 0;
            for (int w2 = 0; w2 < 16; ++w2) t += wc[w2][tid];
            rb[tid] += t;
        }
        __syncthreads();
    }
}

// ---------------- grouped GEMM: C[rows, ND] = A(gathered)[rows, KD] x Bt[e][ND,KD]^T + bias ----------------
template<int KD, int ND, bool RELU, bool GATHER>
__global__ __launch_bounds__(256)
void moe_gemm_kernel(const f16* __restrict__ Abase, const f16* __restrict__ Bt,
                     const float* __restrict__ bias, const int* __restrict__ offsets,
                     const int* __restrict__ tok, f16* __restrict__ Cout) {
    const int e      = blockIdx.z;
    const int rowBeg = offsets[e];
    const int rowEnd = offsets[e + 1];
    const int row0   = rowBeg + blockIdx.y * 128;
    if (row0 >= rowEnd) return;
    const int n0   = blockIdx.x * 128;
    const int tid  = threadIdx.x;
    const int lane = tid & 63;
    const int wid  = tid >> 6;
    const int wr   = (wid >> 1) * 64;
    const int wc   = (wid & 1) * 64;

    __shared__ __align__(16) f16 As[128 * 32];
    __shared__ __align__(16) f16 Bs[128 * 32];

    const f16* Bte = Bt + (size_t)e * ND * KD;

    int arow[2];
    #pragma unroll
    for (int i = 0; i < 2; ++i) {
        int c  = i * 256 + tid;
        int r  = c >> 2;
        int gr = row0 + r;
        if (gr >= rowEnd) gr = rowEnd - 1;
        arow[i] = GATHER ? tok[gr] : gr;
    }

    f32x4 acc[4][4] = {};

    const int nK = KD / 32;
    for (int kt = 0; kt < nK; ++kt) {
        const int k0 = kt * 32;
        #pragma unroll
        for (int i = 0; i < 2; ++i) {   // stage A tile [128 rows][32 k]
            int c  = i * 256 + tid;
            int kc = c & 3;
            gload16(Abase + (size_t)arow[i] * KD + k0 + kc * 8, &As[c * 8]);
        }
        #pragma unroll
        for (int i = 0; i < 2; ++i) {   // stage B tile [128 n][32 k]
            int c = i * 256 + tid;
            int r = c >> 2, kc = c & 3;
            gload16(Bte + (size_t)(n0 + r) * KD + k0 + kc * 8, &Bs[c * 8]);
        }
        __syncthreads();

        const int koff = (lane >> 4) * 8;
        f16x8 af[4], bfr[4];
        #pragma unroll
        for (int m = 0; m < 4; ++m)
            af[m] = *(const f16x8*)&As[(wr + m * 16 + (lane & 15)) * 32 + koff];
        #pragma unroll
        for (int n = 0; n < 4; ++n)
            bfr[n] = *(const f16x8*)&Bs[(wc + n * 16 + (lane & 15)) * 32 + koff];
        #pragma unroll
        for (int m = 0; m < 4; ++m)
            #pragma unroll
            for (int n = 0; n < 4; ++n)
                acc[m][n] = __builtin_amdgcn_mfma_f32_16x16x32_f16(af[m], bfr[n], acc[m][n], 0, 0, 0);
        __syncthreads();
    }

    const int rowsValid = rowEnd - row0;
    #pragma unroll
    for (int m = 0; m < 4; ++m) {
        #pragma unroll
        for (int n = 0; n < 4; ++n) {
            #pragma unroll
            for (int j = 0; j < 4; ++j) {
                int rl  = wr + m * 16 + ((lane >> 4) << 2) + j;
                int col = n0 + wc + n * 16 + (lane & 15);
                if (rl < rowsValid) {
                    float v = acc[m][n][j] + bias[e * ND + col];
                    if (RELU) v = fmaxf(v, 0.f);
                    Cout[(size_t)(row0 + rl) * ND + col] = (f16)v;
                }
            }
        }
    }
}

// ---------------- combine: y[t] = w0*eo[r0] + w1*eo[r1] ----------------
__global__ void combine_kernel(const f16* __restrict__ eo, const int* __restrict__ ros,
                               const float* __restrict__ gw, float* __restrict__ y, int T) {
    int gid = blockIdx.x * 256 + threadIdx.x;
    int t   = gid >> 7;
    if (t >= T) return;
    int c0 = (gid & 127) * 8;
    int r0 = ros[2 * t], r1 = ros[2 * t + 1];
    float w0 = gw[2 * t], w1 = gw[2 * t + 1];
    f16x8 v0 = *(const f16x8*)(eo + (size_t)r0 * DIM + c0);
    f16x8 v1 = *(const f16x8*)(eo + (size_t)r1 * DIM + c0);
    f32x4 o0, o1;
    #pragma unroll
    for (int j = 0; j < 4; ++j) o0[j] = w0 * (float)v0[j] + w1 * (float)v1[j];
    #pragma unroll
    for (int j = 0; j < 4; ++j) o1[j] = w0 * (float)v0[4 + j] + w1 * (float)v1[4 + j];
    *(f32x4*)(y + (size_t)t * DIM + c0)     = o0;
    *(f32x4*)(y + (size_t)t * DIM + c0 + 4) = o1;
}

extern "C" void kernel_launch(void* const* d_in, const int* in_sizes, int n_in,
                              void* d_out, int out_size, void* d_ws, size_t ws_size,
                              hipStream_t stream) {
    const float* x  = (const float*)d_in[0];
    const float* Wg = (const float*)d_in[1];
    const float* W1 = (const float*)d_in[2];
    const float* b1 = (const float*)d_in[3];
    const float* W2 = (const float*)d_in[4];
    const float* b2 = (const float*)d_in[5];
    float* y = (float*)d_out;
    const int T = in_sizes[0] / DIM;   // 8192

    char* ws = (char*)d_ws;
    size_t off = 0;
    auto alloc = [&](size_t bytes) -> char* {
        char* p = ws + off;
        off += (bytes + 255) & ~(size_t)255;
        return p;
    };
    f16* xh   = (f16*)alloc((size_t)T * DIM * 2);
    f16* w1t  = (f16*)alloc((size_t)NEXP * DIM * INTER * 2);
    f16* w2t  = (f16*)alloc((size_t)NEXP * DIM * INTER * 2);
    f16* h    = (f16*)alloc((size_t)2 * T * INTER * 2);
    f16* eo   = (f16*)alloc((size_t)2 * T * DIM * 2);
    float* gw = (float*)alloc((size_t)T * 2 * 4);
    int* gidx = (int*)alloc((size_t)T * 2 * 4);
    int* ros  = (int*)alloc((size_t)T * 2 * 4);
    int* tor  = (int*)alloc((size_t)2 * T * 4);
    int* offsets = (int*)alloc(64 * 4);

    gate_convert_kernel<<<T / 4, 256, 0, stream>>>(x, Wg, xh, gw, gidx, T);
    transpose_conv_kernel<<<dim3(INTER / 64, DIM / 64, NEXP), 256, 0, stream>>>(W1, w1t, DIM, INTER);
    transpose_conv_kernel<<<dim3(DIM / 64, INTER / 64, NEXP), 256, 0, stream>>>(W2, w2t, INTER, DIM);
    route_kernel<<<1, 1024, 0, stream>>>(gidx, offsets, tor, ros, T);
    moe_gemm_kernel<DIM, INTER, true, true>
        <<<dim3(INTER / 128, 64, NEXP), 256, 0, stream>>>(xh, w1t, b1, offsets, tor, h);
    moe_gemm_kernel<INTER, DIM, false, false>
        <<<dim3(DIM / 128, 64, NEXP), 256, 0, stream>>>(h, w2t, b2, offsets, tor, eo);
    combine_kernel<<<(T * DIM / 8 + 255) / 256, 256, 0, stream>>>(eo, ros, gw, y, T);
}